// Round 1
// baseline (388.304 us; speedup 1.0000x reference)
//
#include <hip/hip_runtime.h>

static constexpr int   NPAIRS = 16777216;
static constexpr int   NMOLS  = 4096;
static constexpr float KEF    = 138.96f;
static constexpr int   TPB    = 256;
static constexpr int   BLOCKS = 1024;   // 4 blocks/CU, 16 KB LDS each

__global__ __launch_bounds__(TPB) void zero_out_kernel(float* __restrict__ out) {
    int i = blockIdx.x * TPB + threadIdx.x;
    if (i < NMOLS) out[i] = 0.0f;
}

__device__ __forceinline__ float pair_contrib(const float* __restrict__ q,
                                              int i, int j, float d) {
    // phi(2r): u = 2d; phi = 1 - 10u^3 + 15u^4 - 6u^5 for u < 1, else 0
    float u = 2.0f * d;
    float phi = 0.0f;
    if (u < 1.0f) {
        phi = 1.0f - u * u * u * (10.0f + u * (6.0f * u - 15.0f));
    }
    float chi = phi * rsqrtf(d * d + 1.0f) + (1.0f - phi) / d;
    float c = q[i] * q[j] * chi;
    return (i < j) ? c : 0.0f;   // unique_mask: i==j pairs contribute 0
}

__global__ __launch_bounds__(TPB) void coulomb_kernel(
    const float* __restrict__ q,      // [N_ATOMS]
    const int*   __restrict__ pidx,   // [2, NPAIRS]
    const float* __restrict__ dij,    // [NPAIRS]
    const int*   __restrict__ mol,    // [NPAIRS]
    float*       __restrict__ out)    // [NMOLS] accumulator (pre-zeroed)
{
    __shared__ float bins[NMOLS];
    for (int i = threadIdx.x; i < NMOLS; i += TPB) bins[i] = 0.0f;
    __syncthreads();

    const int4*   pi4 = (const int4*)pidx;
    const int4*   pj4 = (const int4*)(pidx + NPAIRS);
    const float4* d4  = (const float4*)dij;
    const int4*   m4  = (const int4*)mol;

    const int nvec   = NPAIRS / 4;
    const int stride = gridDim.x * TPB;
    for (int v = blockIdx.x * TPB + threadIdx.x; v < nvec; v += stride) {
        int4   ii = pi4[v];
        int4   jj = pj4[v];
        float4 dd = d4[v];
        int4   mm = m4[v];

        float c0 = pair_contrib(q, ii.x, jj.x, dd.x);
        float c1 = pair_contrib(q, ii.y, jj.y, dd.y);
        float c2 = pair_contrib(q, ii.z, jj.z, dd.z);
        float c3 = pair_contrib(q, ii.w, jj.w, dd.w);

        atomicAdd(&bins[mm.x], c0);
        atomicAdd(&bins[mm.y], c1);
        atomicAdd(&bins[mm.z], c2);
        atomicAdd(&bins[mm.w], c3);
    }

    __syncthreads();
    for (int i = threadIdx.x; i < NMOLS; i += TPB) {
        atomicAdd(&out[i], bins[i]);
    }
}

__global__ __launch_bounds__(TPB) void finalize_kernel(float* __restrict__ out,
                                                       const float* __restrict__ pse) {
    int i = blockIdx.x * TPB + threadIdx.x;
    if (i < NMOLS) out[i] = (out[i] + pse[i]) * KEF;
}

extern "C" void kernel_launch(void* const* d_in, const int* in_sizes, int n_in,
                              void* d_out, int out_size, void* d_ws, size_t ws_size,
                              hipStream_t stream) {
    const float* q    = (const float*)d_in[0];   // per_atom_charge  [245760]
    const int*   pidx = (const int*)  d_in[1];   // pair_indices     [2, 16777216]
    const float* dij  = (const float*)d_in[2];   // d_ij             [16777216, 1]
    const int*   mol  = (const int*)  d_in[3];   // atomic_subsystem [16777216]
    const float* pse  = (const float*)d_in[4];   // per_system_energy[4096]
    float* out = (float*)d_out;

    zero_out_kernel<<<NMOLS / TPB, TPB, 0, stream>>>(out);
    coulomb_kernel<<<BLOCKS, TPB, 0, stream>>>(q, pidx, dij, mol, out);
    finalize_kernel<<<NMOLS / TPB, TPB, 0, stream>>>(out, pse);
}